// Round 8
// baseline (94.101 us; speedup 1.0000x reference)
//
#include <hip/hip_runtime.h>

#define BH  64
#define SEQ 4096
#define DH  64
#define NCHUNK 16
#define KTILE  16          // rows per tile
#define NT     16          // tiles per chunk: 256 rows / 16
#define NBUF   4           // LDS tile buffers (k and v each)

// async global->LDS, 16B per lane; LDS dest = wave-uniform base + lane*16
__device__ __forceinline__ void gload_lds16(const float* g, float* l) {
  __builtin_amdgcn_global_load_lds(
      (const __attribute__((address_space(1))) void*)g,
      (__attribute__((address_space(3))) void*)l, 16, 0, 0);
}

// ---------------------------------------------------------------------------
// Kernel 1: partial kv = k^T v over a 256-row chunk. One (b,h,chunk)/block.
// 256 threads = 4 waves; wave grp computes tile rows [grp*4, grp*4+4); each
// lane owns an 8(d) x 8(e) register tile (64 lanes cover 64x64).
// 4-deep double-buffer via global_load_lds with COUNTED vmcnt (never 0 in
// the main loop) + raw s_barrier -> loads stay in flight across barriers.
// Cross-wave partial sums reduced through LDS once at the end.
// LDS 32 KB -> 5 blocks/CU.
// ---------------------------------------------------------------------------
__global__ __launch_bounds__(256) void kv_partial_kernel(
    const float* __restrict__ k, const float* __restrict__ v,
    float* __restrict__ partial) {
  const int t = threadIdx.x;
  const int bh = blockIdx.x >> 4;             // / NCHUNK
  const int chunk = blockIdx.x & (NCHUNK - 1);

  const float* kb = k + (size_t)bh * SEQ * DH + (size_t)chunk * (SEQ / NCHUNK) * DH;
  const float* vb = v + (size_t)bh * SEQ * DH + (size_t)chunk * (SEQ / NCHUNK) * DH;

  // k tiles: [buf*1024, buf*1024+1024)  v tiles: [4096 + buf*1024, ...)
  __shared__ float smem[8192];

  const int g   = t & 63;
  const int grp = t >> 6;
  const int d0 = (g & 7) * 8;
  const int e0 = (g >> 3) * 8;

  float acc[8][8];
#pragma unroll
  for (int i = 0; i < 8; ++i)
#pragma unroll
    for (int j = 0; j < 8; ++j) acc[i][j] = 0.f;

  // stage tile tt into buffer tt&3: 1024 floats per tensor, 1 load/thread ea.
  auto STAGE = [&](int tt) {
    const int buf = tt & (NBUF - 1);
    const int wo = grp * 256;                      // wave's 256-float span
    const float* ksrc = kb + (size_t)tt * (KTILE * DH) + wo + g * 4;
    const float* vsrc = vb + (size_t)tt * (KTILE * DH) + wo + g * 4;
    gload_lds16(ksrc, smem + buf * 1024 + wo);
    gload_lds16(vsrc, smem + 4096 + buf * 1024 + wo);
  };

  auto COMPUTE = [&](int tt) {
    const float* ksb = smem + (tt & (NBUF - 1)) * 1024;
    const float* vsb = smem + 4096 + (tt & (NBUF - 1)) * 1024;
#pragma unroll
    for (int rr = 0; rr < 4; ++rr) {
      const int r = grp * 4 + rr;
      float4 ka0 = *(const float4*)&ksb[r * 64 + d0];
      float4 ka1 = *(const float4*)&ksb[r * 64 + d0 + 4];
      float4 va0 = *(const float4*)&vsb[r * 64 + e0];
      float4 va1 = *(const float4*)&vsb[r * 64 + e0 + 4];
      float kk[8] = {ka0.x, ka0.y, ka0.z, ka0.w, ka1.x, ka1.y, ka1.z, ka1.w};
      float vv[8] = {va0.x, va0.y, va0.z, va0.w, va1.x, va1.y, va1.z, va1.w};
#pragma unroll
      for (int i = 0; i < 8; ++i)
#pragma unroll
        for (int j = 0; j < 8; ++j) acc[i][j] += kk[i] * vv[j];
    }
  };

  // prologue: 3 tiles in flight (6 VMEM per wave)
  STAGE(0); STAGE(1); STAGE(2);

  // steady state: wait tile tt (keep 4 newer loads in flight), barrier,
  // stage tt+3 into the buffer freed by tile tt-1, compute tt.
  for (int tt = 0; tt < NT - 2; ++tt) {
    asm volatile("s_waitcnt vmcnt(4)" ::: "memory");
    __builtin_amdgcn_s_barrier();
    __builtin_amdgcn_sched_barrier(0);
    if (tt + 3 < NT) STAGE(tt + 3);
    COMPUTE(tt);
  }
  // epilogue tiles NT-2, NT-1
  asm volatile("s_waitcnt vmcnt(2)" ::: "memory");
  __builtin_amdgcn_s_barrier();
  __builtin_amdgcn_sched_barrier(0);
  COMPUTE(NT - 2);
  asm volatile("s_waitcnt vmcnt(0)" ::: "memory");
  __builtin_amdgcn_s_barrier();
  __builtin_amdgcn_sched_barrier(0);
  COMPUTE(NT - 1);

  __syncthreads();   // full drain before reusing smem for the reduction

  // ---- cross-wave reduction through LDS ----
  if (grp >= 2) {
    float* reg = smem + (grp - 2) * 4096;
#pragma unroll
    for (int i = 0; i < 8; ++i) {
      float4 w0 = {acc[i][0], acc[i][1], acc[i][2], acc[i][3]};
      float4 w1 = {acc[i][4], acc[i][5], acc[i][6], acc[i][7]};
      *(float4*)&reg[(2 * i) * 256 + g * 4]     = w0;
      *(float4*)&reg[(2 * i + 1) * 256 + g * 4] = w1;
    }
  }
  __syncthreads();
  if (grp < 2) {
    const float* reg = smem + grp * 4096;
#pragma unroll
    for (int i = 0; i < 8; ++i) {
      float4 a = *(const float4*)&reg[(2 * i) * 256 + g * 4];
      float4 b = *(const float4*)&reg[(2 * i + 1) * 256 + g * 4];
      acc[i][0] += a.x; acc[i][1] += a.y; acc[i][2] += a.z; acc[i][3] += a.w;
      acc[i][4] += b.x; acc[i][5] += b.y; acc[i][6] += b.z; acc[i][7] += b.w;
    }
  }
  __syncthreads();
  if (grp == 1) {
#pragma unroll
    for (int i = 0; i < 8; ++i) {
      float4 w0 = {acc[i][0], acc[i][1], acc[i][2], acc[i][3]};
      float4 w1 = {acc[i][4], acc[i][5], acc[i][6], acc[i][7]};
      *(float4*)&smem[(2 * i) * 256 + g * 4]     = w0;
      *(float4*)&smem[(2 * i + 1) * 256 + g * 4] = w1;
    }
  }
  __syncthreads();
  if (grp == 0) {
#pragma unroll
    for (int i = 0; i < 8; ++i) {
      float4 a = *(const float4*)&smem[(2 * i) * 256 + g * 4];
      float4 b = *(const float4*)&smem[(2 * i + 1) * 256 + g * 4];
      acc[i][0] += a.x; acc[i][1] += a.y; acc[i][2] += a.z; acc[i][3] += a.w;
      acc[i][4] += b.x; acc[i][5] += b.y; acc[i][6] += b.z; acc[i][7] += b.w;
    }
    float* pb = partial + (size_t)blockIdx.x * (DH * DH);
#pragma unroll
    for (int i = 0; i < 8; ++i) {
      float4 w0 = {acc[i][0], acc[i][1], acc[i][2], acc[i][3]};
      float4 w1 = {acc[i][4], acc[i][5], acc[i][6], acc[i][7]};
      *(float4*)&pb[(d0 + i) * 64 + e0]     = w0;
      *(float4*)&pb[(d0 + i) * 64 + e0 + 4] = w1;
    }
  }
}

// ---------------------------------------------------------------------------
// Kernel 2: reduce partials -> kvf [BH][64*64]. 256 blocks x 256 threads
// covers 65536 float4 slots.
// ---------------------------------------------------------------------------
__global__ __launch_bounds__(256) void kv_reduce_kernel(
    const float* __restrict__ partial, float* __restrict__ kvf) {
  const int gid = blockIdx.x * 256 + threadIdx.x;
  const int bh = gid >> 10;
  const int idx = gid & 1023;
  float4 s = {0.f, 0.f, 0.f, 0.f};
  for (int c = 0; c < NCHUNK; ++c) {
    const float4* p = (const float4*)(partial + ((size_t)bh * NCHUNK + c) * (DH * DH));
    float4 x = p[idx];
    s.x += x.x; s.y += x.y; s.z += x.z; s.w += x.w;
  }
  ((float4*)kvf)[gid] = s;
}

// ---------------------------------------------------------------------------
// Kernel 3: out = q @ kv. Block = 64 q-rows. Thread = 1 row x 16 cols.
// Entire q row hoisted to registers up front (16 independent dwordx4 issued
// before the barrier -> overlap kv staging latency). kv in LDS, broadcast
// reads. Fully unrolled d-loop.
// ---------------------------------------------------------------------------
__global__ __launch_bounds__(256) void out_kernel(
    const float* __restrict__ q, const float* __restrict__ kvf,
    float* __restrict__ out) {
  const int t = threadIdx.x;
  const int bh = blockIdx.x >> 6;
  const int rb = blockIdx.x & 63;
  const int row = rb * 64 + (t >> 2);
  const int c0 = (t & 3) * 16;

  __shared__ float kv_lds[64 * 64];

  const float4* gkv4 = (const float4*)(kvf + (size_t)bh * (DH * DH));
  float4* kv4 = (float4*)kv_lds;
#pragma unroll
  for (int j = 0; j < 4; ++j) kv4[t + j * 256] = gkv4[t + j * 256];

  // issue all q loads before the barrier
  const float* qrow = q + (size_t)bh * SEQ * DH + (size_t)row * DH;
  float4 qv[16];
#pragma unroll
  for (int i = 0; i < 16; ++i) qv[i] = *(const float4*)&qrow[i * 4];

  __syncthreads();

  float acc[16];
#pragma unroll
  for (int j = 0; j < 16; ++j) acc[j] = 0.f;

#pragma unroll
  for (int dc = 0; dc < 16; ++dc) {
    float qs[4] = {qv[dc].x, qv[dc].y, qv[dc].z, qv[dc].w};
#pragma unroll
    for (int dd = 0; dd < 4; ++dd) {
      const float* kr = &kv_lds[(dc * 4 + dd) * 64 + c0];
      float4 k0 = *(const float4*)&kr[0];
      float4 k1 = *(const float4*)&kr[4];
      float4 k2 = *(const float4*)&kr[8];
      float4 k3 = *(const float4*)&kr[12];
      const float qsv = qs[dd];
      acc[0]  += qsv * k0.x; acc[1]  += qsv * k0.y;
      acc[2]  += qsv * k0.z; acc[3]  += qsv * k0.w;
      acc[4]  += qsv * k1.x; acc[5]  += qsv * k1.y;
      acc[6]  += qsv * k1.z; acc[7]  += qsv * k1.w;
      acc[8]  += qsv * k2.x; acc[9]  += qsv * k2.y;
      acc[10] += qsv * k2.z; acc[11] += qsv * k2.w;
      acc[12] += qsv * k3.x; acc[13] += qsv * k3.y;
      acc[14] += qsv * k3.z; acc[15] += qsv * k3.w;
    }
  }

  float* ob = out + (size_t)bh * SEQ * DH + (size_t)row * DH + c0;
#pragma unroll
  for (int j = 0; j < 4; ++j) {
    float4 w = {acc[4 * j + 0], acc[4 * j + 1], acc[4 * j + 2], acc[4 * j + 3]};
    *(float4*)&ob[4 * j] = w;
  }
}

// ---------------------------------------------------------------------------
extern "C" void kernel_launch(void* const* d_in, const int* in_sizes, int n_in,
                              void* d_out, int out_size, void* d_ws, size_t ws_size,
                              hipStream_t stream) {
  const float* q = (const float*)d_in[0];
  const float* k = (const float*)d_in[1];
  const float* v = (const float*)d_in[2];
  float* out = (float*)d_out;

  float* kvf = (float*)d_ws;                      // [BH][64*64] = 1 MB
  float* partial = kvf + (size_t)BH * DH * DH;    // [BH*NCHUNK][64*64] = 16 MB

  hipLaunchKernelGGL(kv_partial_kernel, dim3(BH * NCHUNK), dim3(256), 0, stream,
                     k, v, partial);
  hipLaunchKernelGGL(kv_reduce_kernel, dim3(256), dim3(256), 0, stream,
                     partial, kvf);
  hipLaunchKernelGGL(out_kernel, dim3(BH * 64), dim3(256), 0, stream,
                     q, kvf, out);
}